// Round 17
// baseline (263.379 us; speedup 1.0000x reference)
//
#include <hip/hip_runtime.h>
#include <hip/hip_bf16.h>
#include <hip/hip_fp16.h>

// BinaryTreeLSTM  B=64, L=1024, IN_DIM=300, MEM=256 — v17.
// = v16 (v12 baseline, 256.6us) with mfma_gemm enlarged to 256 rows x 128 G
// (512 thr, 8 waves 4wm x 2wn, wave tile 64r x 64G unchanged), this time with
// CORRECT __launch_bounds__(512,4): VGPR cap 128 (need ~120), 4 waves/SIMD,
// 2 blocks/CU (48KB LDS). 128 MFMA (~620cy) per block-K-step covers the
// staging latency that v12's 64-MFMA step exposed (MfmaUtil 22%).
// v15 already proved this kernel's numerics (passed, absmax 0.015625);
// only the occupancy bound changed. Tail/prep = v12 verbatim.

typedef __attribute__((ext_vector_type(8))) short bf16x8;
typedef __attribute__((ext_vector_type(4))) float f32x4;

__device__ __forceinline__ float fsig(float x)  { return 1.f / (1.f + __expf(-x)); }
__device__ __forceinline__ float ftanh(float x) { return 1.f - 2.f / (__expf(2.f * x) + 1.f); }
__device__ __forceinline__ ushort f2bf(float x) {
    __hip_bfloat16 b = __float2bfloat16(x);
    return *reinterpret_cast<ushort*>(&b);
}

__device__ __forceinline__ void gld_lds16(const void* g, void* l) {
    __builtin_amdgcn_global_load_lds((const __attribute__((address_space(1))) void*)g,
                                     (__attribute__((address_space(3))) void*)l, 16, 0, 0);
}

// ---------------- prep: pack level + pack leaf + biases + embs->bf16 ----------------
__global__ void prep(const float* __restrict__ Wl,  const float* __restrict__ Wr,
                     const float* __restrict__ bl,  const float* __restrict__ br,
                     const float* __restrict__ Wcx, const float* __restrict__ Wox,
                     const float* __restrict__ bcx, const float* __restrict__ box,
                     const float* __restrict__ embs,
                     ushort* __restrict__ Wb2, ushort* __restrict__ WbL,
                     float* __restrict__ bp2, float* __restrict__ bpL,
                     ushort* __restrict__ embsB)
{
    const int gid = blockIdx.x * 256 + threadIdx.x;     // 1024 blocks -> 262144
    for (int i = gid; i < 524288; i += 262144) {
        int e = i & 7, slot = (i >> 3) & 3, o = (i >> 5) & 255;
        int g = (i >> 13) & 3, t = i >> 15;
        int q = slot ^ ((o >> 1) & 3);
        int k = t * 32 + q * 8 + e;
        float v = (k < 256) ? Wl[(g * 256 + o) * 256 + k]
                            : Wr[(g * 256 + o) * 256 + (k - 256)];
        Wb2[i] = f2bf(v);
    }
    if (gid < 163840) {
        int e = gid & 7, slot = (gid >> 3) & 3, o = (gid >> 5) & 255;
        int g = (gid >> 13) & 1, t = gid >> 14;
        int q = slot ^ ((o >> 1) & 3);
        int k = t * 32 + q * 8 + e;
        float v = 0.f;
        if (k < 300) v = g ? Wox[o * 300 + k] : Wcx[o * 300 + k];
        WbL[gid] = f2bf(v);
    }
    if (gid < 1024) bp2[gid] = bl[gid] + br[gid];
    if (gid < 512) {
        int g = gid >> 8, o = gid & 255;
        bpL[gid] = g ? box[o] : bcx[o];
    }
    for (int i = gid; i < 65536 * 80; i += 262144) {
        int row = i / 80;
        int k = (i - row * 80) * 4;
        float4 v = make_float4(0.f, 0.f, 0.f, 0.f);
        if (k < 300) v = *(const float4*)(embs + (size_t)row * 300 + k);
        ushort4 o4;
        o4.x = f2bf(v.x); o4.y = f2bf(v.y); o4.z = f2bf(v.z); o4.w = f2bf(v.w);
        *(ushort4*)(embsB + (size_t)row * 320 + k) = o4;
    }
}

// ---------------- big-level GEMM: 256r x 128G block, 8 waves, 2 blocks/CU ----------------
// Wave tile 64r x 64G (4 m-frags x 4 f-frags) — identical to v12's wave.
// v4-verified swizzles (row-invariant under +64/+128 offsets).
// MODE 0 = leaf (NG=2), 1 = level (fp16 c, bf16 h).

template<int NG, int HALVES, int MODE>
__global__ __launch_bounds__(512, 4)
void mfma_gemm(const ushort* __restrict__ A,
               const ushort* __restrict__ Wb,
               const float* __restrict__ bp,
               const __half* __restrict__ Cprev,
               __half* __restrict__ c_out,
               ushort* __restrict__ h_out,
               int M)
{
    constexpr int K = HALVES * 32;
    constexpr int OW = 128 / NG;
    __shared__ __align__(16) ushort As[2][1024 * 8];   // 256 rows x 32 k
    __shared__ __align__(16) ushort Bs[2][512 * 8];    // 128 G x 32 k

    const int tid = threadIdx.x;
    const int wid = tid >> 6, ln = tid & 63;
    const int lq = ln >> 4, lr = ln & 15;
    const int wm = wid >> 1, wn = wid & 1;             // wm 0..3, wn 0..1
    const int rowBlk = blockIdx.x * 256;
    const int o0 = blockIdx.y * OW;

    f32x4 acc[4][4];
#pragma unroll
    for (int m = 0; m < 4; ++m)
#pragma unroll
        for (int f = 0; f < 4; ++f) acc[m][f] = f32x4{0.f, 0.f, 0.f, 0.f};

    // A staging: chunks c = tid (rows 0..127) and tid+512 (rows 128..255)
    const int ar = tid >> 2;
    const int aq = ((tid & 3) - ((tid >> 3) & 3)) & 3;   // q = (slot - ((row>>1)&3))&3
    const ushort* aP0 = A + (size_t)min(rowBlk + ar, M - 1) * K + aq * 8;
    const ushort* aP1 = A + (size_t)min(rowBlk + 128 + ar, M - 1) * K + aq * 8;
    // B staging: chunk c = tid (512 chunks)
    const int bj = tid >> 2, bs = tid & 3;
    const int bg = bj / OW, bo = o0 + (bj & (OW - 1));
    const ushort* bP = Wb + ((size_t)bg * 1024 + bo * 4 + bs) * 8;
    constexpr size_t BSTR = (size_t)NG * 1024 * 8;

    const int aSw = (lq + ((lr >> 1) & 3)) & 3;
    const int bSw = lq ^ ((lr >> 1) & 3);
    int aOff[4];
#pragma unroll
    for (int m = 0; m < 4; ++m)
        aOff[m] = ((wm * 64 + m * 16 + lr) * 4 + aSw) * 8;
    int bOff[4];
#pragma unroll
    for (int f = 0; f < 4; ++f)
        bOff[f] = ((f * 32 + wn * 16 + lr) * 4 + bSw) * 8;

    gld_lds16(aP0, &As[0][tid * 8]);
    gld_lds16(aP1, &As[0][(tid + 512) * 8]);
    gld_lds16(bP,  &Bs[0][tid * 8]);

#pragma unroll
    for (int h = 0; h < HALVES; ++h) {
        __syncthreads();               // drains vmcnt -> buf[cur] staged
        const int cur = h & 1;
        if (h + 1 < HALVES) {
            gld_lds16(aP0 + (size_t)(h + 1) * 32, &As[cur ^ 1][tid * 8]);
            gld_lds16(aP1 + (size_t)(h + 1) * 32, &As[cur ^ 1][(tid + 512) * 8]);
            gld_lds16(bP + (size_t)(h + 1) * BSTR, &Bs[cur ^ 1][tid * 8]);
        }
        bf16x8 a[4];
#pragma unroll
        for (int m = 0; m < 4; ++m)
            a[m] = *(const bf16x8*)&As[cur][aOff[m]];
#pragma unroll
        for (int f = 0; f < 4; ++f) {
            bf16x8 b = *(const bf16x8*)&Bs[cur][bOff[f]];
#pragma unroll
            for (int m = 0; m < 4; ++m)
                acc[m][f] = __builtin_amdgcn_mfma_f32_16x16x32_bf16(a[m], b, acc[m][f], 0, 0, 0);
        }
    }

#pragma unroll
    for (int m = 0; m < 4; ++m) {
        const int row0 = rowBlk + wm * 64 + m * 16 + lq * 4;
        if constexpr (MODE == 0) {
#pragma unroll
            for (int ob = 0; ob < 2; ++ob) {
                const int col = o0 + ob * 32 + wn * 16 + lr;
                const float bc = bp[col], bo = bp[256 + col];
#pragma unroll
                for (int j = 0; j < 4; ++j) {
                    int row = row0 + j;
                    if (row < M) {
                        float cv = acc[m][ob][j] + bc;
                        float ov = acc[m][2 + ob][j] + bo;
                        c_out[(size_t)row * 256 + col] = __float2half(cv);
                        h_out[(size_t)row * 256 + col] = f2bf(fsig(ov) * ftanh(cv));
                    }
                }
            }
        } else {
            const int col = o0 + wn * 16 + lr;
            const float bi  = bp[col],       blf = bp[256 + col];
            const float brf = bp[512 + col], bu  = bp[768 + col];
#pragma unroll
            for (int j = 0; j < 4; ++j) {
                int row = row0 + j;
                if (row < M) {
                    float gi = fsig(acc[m][0][j] + bi);
                    float lf = fsig(acc[m][1][j] + blf);
                    float rf = fsig(acc[m][2][j] + brf);
                    float gu = ftanh(acc[m][3][j] + bu);
                    float lc = __half2float(Cprev[(size_t)row * 512 + col]);
                    float rc = __half2float(Cprev[(size_t)row * 512 + 256 + col]);
                    float cv = gi * gu + lf * lc + rf * rc;
                    c_out[(size_t)row * 256 + col] = __float2half(cv);
                    h_out[(size_t)row * 256 + col] = f2bf(ftanh(cv));
                }
            }
        }
    }
}

// ---------------- tail: out-np 32..1, one block per batch (v12 verbatim) ----------------
__global__ __launch_bounds__(512, 1)
void tail_lstm(const ushort* __restrict__ hin,   // (4096,256) bf16: 64 x 64 nodes
               const __half* __restrict__ cin,   // (4096,256) fp16
               const ushort* __restrict__ Wb,    // packed level weights
               const float* __restrict__ bp,     // (1024)
               float* __restrict__ dout)
{
    __shared__ __align__(16) ushort HA[32 * 256];
    __shared__ __align__(16) float  CA[32 * 256];
    __shared__ __align__(16) ushort HB[16 * 256];
    __shared__ __align__(16) float  CB[16 * 256];

    const int b = blockIdx.x;
    const int tid = threadIdx.x;
    const int wid = tid >> 6, ln = tid & 63;
    const int lq = ln >> 4, lr = ln & 15;

    int o_[2], sl_[2];
    const ushort* bB[2];
#pragma unroll
    for (int of = 0; of < 2; ++of) {
        o_[of] = wid * 32 + of * 16 + lr;
        sl_[of] = lq ^ ((o_[of] >> 1) & 3);
        bB[of] = Wb + (size_t)(o_[of] * 4 + sl_[of]) * 8;
    }
    const float bi0  = bp[o_[0]],       blf0 = bp[256 + o_[0]];
    const float brf0 = bp[512 + o_[0]], bu0  = bp[768 + o_[0]];
    const float bi1  = bp[o_[1]],       blf1 = bp[256 + o_[1]];
    const float brf1 = bp[512 + o_[1]], bu1  = bp[768 + o_[1]];

    // ---- prologue level: np_out = 32 (MC = 2), input from global
    {
        const ushort* hbase = hin + (size_t)b * 64 * 256;
        f32x4 acc[2][2][4];
#pragma unroll
        for (int m = 0; m < 2; ++m)
#pragma unroll
            for (int of = 0; of < 2; ++of)
#pragma unroll
                for (int g = 0; g < 4; ++g) acc[m][of][g] = f32x4{0.f, 0.f, 0.f, 0.f};

        bf16x8 b0[2][4], b1[2][4], a0[2], a1[2];
#pragma unroll
        for (int of = 0; of < 2; ++of)
#pragma unroll
            for (int g = 0; g < 4; ++g)
                b0[of][g] = *(const bf16x8*)(bB[of] + (size_t)g * 8192);
#pragma unroll
        for (int m = 0; m < 2; ++m) {
            int pr = 32 * m + 2 * lr;
            a0[m] = *(const bf16x8*)(hbase + (size_t)pr * 256 + lq * 8);
        }

#pragma unroll 1
        for (int ks = 0; ks < 16; ks += 2) {
            if (ks + 1 < 16) {
#pragma unroll
                for (int of = 0; of < 2; ++of)
#pragma unroll
                    for (int g = 0; g < 4; ++g)
                        b1[of][g] = *(const bf16x8*)(bB[of] + (size_t)((ks + 1) * 4 + g) * 8192);
#pragma unroll
                for (int m = 0; m < 2; ++m) {
                    int pr = 32 * m + 2 * lr + ((ks + 1) >> 3);
                    int pc = lq + ((ks + 1) & 7) * 4;
                    a1[m] = *(const bf16x8*)(hbase + (size_t)pr * 256 + pc * 8);
                }
            }
#pragma unroll
            for (int m = 0; m < 2; ++m)
#pragma unroll
                for (int of = 0; of < 2; ++of)
#pragma unroll
                    for (int g = 0; g < 4; ++g)
                        acc[m][of][g] = __builtin_amdgcn_mfma_f32_16x16x32_bf16(a0[m], b0[of][g], acc[m][of][g], 0, 0, 0);
            if (ks + 2 < 16) {
#pragma unroll
                for (int of = 0; of < 2; ++of)
#pragma unroll
                    for (int g = 0; g < 4; ++g)
                        b0[of][g] = *(const bf16x8*)(bB[of] + (size_t)((ks + 2) * 4 + g) * 8192);
#pragma unroll
                for (int m = 0; m < 2; ++m) {
                    int pr = 32 * m + 2 * lr + ((ks + 2) >> 3);
                    int pc = lq + ((ks + 2) & 7) * 4;
                    a0[m] = *(const bf16x8*)(hbase + (size_t)pr * 256 + pc * 8);
                }
            }
#pragma unroll
            for (int m = 0; m < 2; ++m)
#pragma unroll
                for (int of = 0; of < 2; ++of)
#pragma unroll
                    for (int g = 0; g < 4; ++g)
                        acc[m][of][g] = __builtin_amdgcn_mfma_f32_16x16x32_bf16(a1[m], b1[of][g], acc[m][of][g], 0, 0, 0);
        }

        const __half* cbase = cin + (size_t)b * 64 * 256;
#pragma unroll
        for (int m = 0; m < 2; ++m)
#pragma unroll
        for (int of = 0; of < 2; ++of) {
            const int col = o_[of];
            const float vbi  = of ? bi1 : bi0,   vblf = of ? blf1 : blf0;
            const float vbrf = of ? brf1 : brf0, vbu  = of ? bu1 : bu0;
#pragma unroll
            for (int j = 0; j < 4; ++j) {
                int row = m * 16 + lq * 4 + j;
                float gi = fsig(acc[m][of][0][j] + vbi);
                float lf = fsig(acc[m][of][1][j] + vblf);
                float rf = fsig(acc[m][of][2][j] + vbrf);
                float gu = ftanh(acc[m][of][3][j] + vbu);
                float lc = __half2float(cbase[(size_t)(2 * row) * 256 + col]);
                float rc = __half2float(cbase[(size_t)(2 * row + 1) * 256 + col]);
                float cv = gi * gu + lf * lc + rf * rc;
                float hv = ftanh(cv);
                CA[row * 256 + col] = cv;
                HA[row * 256 + (((col >> 3) ^ ((row >> 1) & 7)) * 8) + (col & 7)] = f2bf(hv);
            }
        }
        __syncthreads();
    }

    // ---- dynamic levels: np_out = 16..1
#pragma unroll 1
    for (int lvl = 1; lvl < 6; ++lvl) {
        const int npo = 32 >> lvl;
        const ushort* Hin = (lvl & 1) ? HA : HB;
        ushort*       Hout = (lvl & 1) ? HB : HA;
        const float*  Cin = (lvl & 1) ? CA : CB;
        float*        Cout = (lvl & 1) ? CB : CA;

        f32x4 acc[2][4];
#pragma unroll
        for (int of = 0; of < 2; ++of)
#pragma unroll
            for (int g = 0; g < 4; ++g) acc[of][g] = f32x4{0.f, 0.f, 0.f, 0.f};

        bf16x8 b0[2][4], b1[2][4], a0, a1;
#pragma unroll
        for (int of = 0; of < 2; ++of)
#pragma unroll
            for (int g = 0; g < 4; ++g)
                b0[of][g] = *(const bf16x8*)(bB[of] + (size_t)g * 8192);
        {
            int pr = 2 * lr;
            a0 = *(const bf16x8*)&Hin[pr * 256 + ((lq ^ ((pr >> 1) & 7)) * 8)];
        }

#pragma unroll 1
        for (int ks = 0; ks < 16; ks += 2) {
            if (ks + 1 < 16) {
#pragma unroll
                for (int of = 0; of < 2; ++of)
#pragma unroll
                    for (int g = 0; g < 4; ++g)
                        b1[of][g] = *(const bf16x8*)(bB[of] + (size_t)((ks + 1) * 4 + g) * 8192);
                int pr = 2 * lr + ((ks + 1) >> 3), pc = lq + ((ks + 1) & 7) * 4;
                a1 = *(const bf16x8*)&Hin[pr * 256 + ((pc ^ ((pr >> 1) & 7)) * 8)];
            }
#pragma unroll
            for (int of = 0; of < 2; ++of)
#pragma unroll
                for (int g = 0; g < 4; ++g)
                    acc[of][g] = __builtin_amdgcn_mfma_f32_16x16x32_bf16(a0, b0[of][g], acc[of][g], 0, 0, 0);
            if (ks + 2 < 16) {
#pragma unroll
                for (int of = 0; of < 2; ++of)
#pragma unroll
                    for (int g = 0; g < 4; ++g)
                        b0[of][g] = *(const bf16x8*)(bB[of] + (size_t)((ks + 2) * 4 + g) * 8192);
                int pr = 2 * lr + ((ks + 2) >> 3), pc = lq + ((ks + 2) & 7) * 4;
                a0 = *(const bf16x8*)&Hin[pr * 256 + ((pc ^ ((pr >> 1) & 7)) * 8)];
            }
#pragma unroll
            for (int of = 0; of < 2; ++of)
#pragma unroll
                for (int g = 0; g < 4; ++g)
                    acc[of][g] = __builtin_amdgcn_mfma_f32_16x16x32_bf16(a1, b1[of][g], acc[of][g], 0, 0, 0);
        }

#pragma unroll
        for (int of = 0; of < 2; ++of) {
            const int col = o_[of];
            const float vbi  = of ? bi1 : bi0,   vblf = of ? blf1 : blf0;
            const float vbrf = of ? brf1 : brf0, vbu  = of ? bu1 : bu0;
#pragma unroll
            for (int j = 0; j < 4; ++j) {
                int row = lq * 4 + j;
                if (row < npo) {
                    float gi = fsig(acc[of][0][j] + vbi);
                    float lf = fsig(acc[of][1][j] + vblf);
                    float rf = fsig(acc[of][2][j] + vbrf);
                    float gu = ftanh(acc[of][3][j] + vbu);
                    float lc = Cin[(2 * row) * 256 + col];
                    float rc = Cin[(2 * row + 1) * 256 + col];
                    float cv = gi * gu + lf * lc + rf * rc;
                    float hv = ftanh(cv);
                    if (lvl == 5) {
                        dout[b * 256 + col] = cv;
                        dout[16384 + b * 256 + col] = hv;
                    } else {
                        Cout[row * 256 + col] = cv;
                        Hout[row * 256 + (((col >> 3) ^ ((row >> 1) & 7)) * 8) + (col & 7)] = f2bf(hv);
                    }
                }
            }
        }
        __syncthreads();
    }
}

// ---------------- host ----------------

extern "C" void kernel_launch(void* const* d_in, const int* in_sizes, int n_in,
                              void* d_out, int out_size, void* d_ws, size_t ws_size,
                              hipStream_t stream)
{
    const float* embs = (const float*)d_in[0];
    const float* Wcx  = (const float*)d_in[1];
    const float* bcx  = (const float*)d_in[2];
    const float* Wox  = (const float*)d_in[3];
    const float* box  = (const float*)d_in[4];
    const float* Wl   = (const float*)d_in[5];
    const float* bl   = (const float*)d_in[6];
    const float* Wr   = (const float*)d_in[7];
    const float* br   = (const float*)d_in[8];

    char* p = (char*)d_ws;
    ushort* Wb2 = (ushort*)p;  p += (size_t)524288 * 2;
    ushort* WbL = (ushort*)p;  p += (size_t)163840 * 2;
    float*  bp2 = (float*)p;   p += 1024 * 4;
    float*  bpL = (float*)p;   p += 512 * 4;
    __half* c0  = (__half*)p;  p += (size_t)65536 * 256 * 2;   // 32 MB
    ushort* h0  = (ushort*)p;  p += (size_t)65536 * 256 * 2;   // 32 MB
    char* X = p;
    ushort* embsB = (ushort*)X;                                 // 40 MB (dead after leaf)
    __half* cA = (__half*)X;                                    // 16 MB (32768,256)
    ushort* hA = (ushort*)(X + (size_t)16 * 1024 * 1024);       // 16 MB
    __half* cB = (__half*)(X + (size_t)32 * 1024 * 1024);       //  8 MB (16384,256)
    ushort* hB = (ushort*)(X + (size_t)40 * 1024 * 1024);       //  8 MB

    prep<<<1024, 256, 0, stream>>>(Wl, Wr, bl, br, Wcx, Wox, bcx, box, embs,
                                   Wb2, WbL, bp2, bpL, embsB);

    // leaf: (65536,320) @ (320, 2*256) -> c0 fp16, h0 bf16
    mfma_gemm<2, 10, 0><<<dim3(256, 4), 512, 0, stream>>>(
        embsB, WbL, bpL, nullptr, c0, h0, 65536);

    // np=512: h0 (32768,512), c0 -> cA,hA
    mfma_gemm<4, 16, 1><<<dim3(128, 8), 512, 0, stream>>>(
        h0, Wb2, bp2, c0, cA, hA, 32768);
    // np=256: hA, cA -> cB,hB
    mfma_gemm<4, 16, 1><<<dim3(64, 8), 512, 0, stream>>>(
        hA, Wb2, bp2, cA, cB, hB, 16384);
    // np=128: hB, cB -> cA,hA
    mfma_gemm<4, 16, 1><<<dim3(32, 8), 512, 0, stream>>>(
        hB, Wb2, bp2, cB, cA, hA, 8192);
    // np=64: hA, cA -> cB,hB
    mfma_gemm<4, 16, 1><<<dim3(16, 8), 512, 0, stream>>>(
        hA, Wb2, bp2, cA, cB, hB, 4096);

    // tail: np 32..1 (input hB (4096,256) bf16, cB fp16) -> d_out
    tail_lstm<<<64, 512, 0, stream>>>(
        hB, cB, Wb2, bp2, (float*)d_out);
}

// Round 18
// 256.489 us; speedup vs baseline: 1.0269x; 1.0269x over previous
//
#include <hip/hip_runtime.h>
#include <hip/hip_bf16.h>
#include <hip/hip_fp16.h>

// BinaryTreeLSTM  B=64, L=1024, IN_DIM=300, MEM=256 — v18.
// = v16 (best, 256.6us) + ks-rotation in tail_lstm: each block walks the
// 1MB weight stream starting at a different K-offset (rot = blockIdx>>3,
// distinct per co-XCD block under b%8 round-robin), breaking same-cache-line
// lockstep contention at the L2 slices (diagnosed: 64 identical instruction
// streams -> 8-way same-line serialization per XCD -> 91 GB/s/CU ingest).
// Accumulation over K is order-independent; numerics unchanged to rounding.

typedef __attribute__((ext_vector_type(8))) short bf16x8;
typedef __attribute__((ext_vector_type(4))) float f32x4;

__device__ __forceinline__ float fsig(float x)  { return 1.f / (1.f + __expf(-x)); }
__device__ __forceinline__ float ftanh(float x) { return 1.f - 2.f / (__expf(2.f * x) + 1.f); }
__device__ __forceinline__ ushort f2bf(float x) {
    __hip_bfloat16 b = __float2bfloat16(x);
    return *reinterpret_cast<ushort*>(&b);
}

__device__ __forceinline__ void gld_lds16(const void* g, void* l) {
    __builtin_amdgcn_global_load_lds((const __attribute__((address_space(1))) void*)g,
                                     (__attribute__((address_space(3))) void*)l, 16, 0, 0);
}

// ---------------- prep: pack level + pack leaf + biases + embs->bf16 ----------------
__global__ void prep(const float* __restrict__ Wl,  const float* __restrict__ Wr,
                     const float* __restrict__ bl,  const float* __restrict__ br,
                     const float* __restrict__ Wcx, const float* __restrict__ Wox,
                     const float* __restrict__ bcx, const float* __restrict__ box,
                     const float* __restrict__ embs,
                     ushort* __restrict__ Wb2, ushort* __restrict__ WbL,
                     float* __restrict__ bp2, float* __restrict__ bpL,
                     ushort* __restrict__ embsB)
{
    const int gid = blockIdx.x * 256 + threadIdx.x;     // 1024 blocks -> 262144
    for (int i = gid; i < 524288; i += 262144) {
        int e = i & 7, slot = (i >> 3) & 3, o = (i >> 5) & 255;
        int g = (i >> 13) & 3, t = i >> 15;
        int q = slot ^ ((o >> 1) & 3);
        int k = t * 32 + q * 8 + e;
        float v = (k < 256) ? Wl[(g * 256 + o) * 256 + k]
                            : Wr[(g * 256 + o) * 256 + (k - 256)];
        Wb2[i] = f2bf(v);
    }
    if (gid < 163840) {
        int e = gid & 7, slot = (gid >> 3) & 3, o = (gid >> 5) & 255;
        int g = (gid >> 13) & 1, t = gid >> 14;
        int q = slot ^ ((o >> 1) & 3);
        int k = t * 32 + q * 8 + e;
        float v = 0.f;
        if (k < 300) v = g ? Wox[o * 300 + k] : Wcx[o * 300 + k];
        WbL[gid] = f2bf(v);
    }
    if (gid < 1024) bp2[gid] = bl[gid] + br[gid];
    if (gid < 512) {
        int g = gid >> 8, o = gid & 255;
        bpL[gid] = g ? box[o] : bcx[o];
    }
    for (int i = gid; i < 65536 * 80; i += 262144) {
        int row = i / 80;
        int k = (i - row * 80) * 4;
        float4 v = make_float4(0.f, 0.f, 0.f, 0.f);
        if (k < 300) v = *(const float4*)(embs + (size_t)row * 300 + k);
        ushort4 o4;
        o4.x = f2bf(v.x); o4.y = f2bf(v.y); o4.z = f2bf(v.z); o4.w = f2bf(v.w);
        *(ushort4*)(embsB + (size_t)row * 320 + k) = o4;
    }
}

// ---------------- v10/v12 big-level GEMM (proven), c in fp16 ----------------
template<int NG, int HALVES, int MODE>
__global__ __launch_bounds__(256, 4)
void mfma_gemm(const ushort* __restrict__ A,
               const ushort* __restrict__ Wb,
               const float* __restrict__ bp,
               const __half* __restrict__ Cprev,
               __half* __restrict__ c_out,
               ushort* __restrict__ h_out,
               int M)
{
    constexpr int K = HALVES * 32;
    constexpr int OW = 128 / NG;
    __shared__ __align__(16) ushort As[2][512 * 8];
    __shared__ __align__(16) ushort Bs[2][512 * 8];

    const int tid = threadIdx.x;
    const int wid = tid >> 6, ln = tid & 63;
    const int lq = ln >> 4, lr = ln & 15;
    const int wm = wid >> 1, wn = wid & 1;
    const int rowBlk = blockIdx.x * 128;
    const int o0 = blockIdx.y * OW;

    f32x4 acc[4][4];
#pragma unroll
    for (int m = 0; m < 4; ++m)
#pragma unroll
        for (int f = 0; f < 4; ++f) acc[m][f] = f32x4{0.f, 0.f, 0.f, 0.f};

    const int ar0 = tid >> 2,  as0 = tid & 3;
    const int ar1 = ar0 + 64;
    const int aq0 = (as0 - ((ar0 >> 1) & 3)) & 3;
    const int aq1 = (as0 - ((ar1 >> 1) & 3)) & 3;
    const ushort* aP0 = A + (size_t)min(rowBlk + ar0, M - 1) * K + aq0 * 8;
    const ushort* aP1 = A + (size_t)min(rowBlk + ar1, M - 1) * K + aq1 * 8;
    const int bj0 = tid >> 2,        bs0 = tid & 3;
    const int bj1 = (tid + 256) >> 2;
    const int bg0 = bj0 / OW, bo0 = o0 + (bj0 & (OW - 1));
    const int bg1 = bj1 / OW, bo1 = o0 + (bj1 & (OW - 1));
    const ushort* bP0 = Wb + ((size_t)bg0 * 1024 + bo0 * 4 + bs0) * 8;
    const ushort* bP1 = Wb + ((size_t)bg1 * 1024 + bo1 * 4 + bs0) * 8;
    constexpr size_t BSTR = (size_t)NG * 1024 * 8;

    const int aSw = (lq + ((lr >> 1) & 3)) & 3;
    const int bSw = lq ^ ((lr >> 1) & 3);
    int aOff[4];
#pragma unroll
    for (int m = 0; m < 4; ++m)
        aOff[m] = ((wm * 64 + m * 16 + lr) * 4 + aSw) * 8;
    int bOff[4];
#pragma unroll
    for (int f = 0; f < 4; ++f)
        bOff[f] = ((f * 32 + wn * 16 + lr) * 4 + bSw) * 8;

    gld_lds16(aP0, &As[0][tid * 8]);
    gld_lds16(aP1, &As[0][(tid + 256) * 8]);
    gld_lds16(bP0, &Bs[0][tid * 8]);
    gld_lds16(bP1, &Bs[0][(tid + 256) * 8]);

#pragma unroll
    for (int h = 0; h < HALVES; ++h) {
        __syncthreads();
        const int cur = h & 1;
        if (h + 1 < HALVES) {
            gld_lds16(aP0 + (size_t)(h + 1) * 32, &As[cur ^ 1][tid * 8]);
            gld_lds16(aP1 + (size_t)(h + 1) * 32, &As[cur ^ 1][(tid + 256) * 8]);
            gld_lds16(bP0 + (size_t)(h + 1) * BSTR, &Bs[cur ^ 1][tid * 8]);
            gld_lds16(bP1 + (size_t)(h + 1) * BSTR, &Bs[cur ^ 1][(tid + 256) * 8]);
        }
        bf16x8 a[4];
#pragma unroll
        for (int m = 0; m < 4; ++m)
            a[m] = *(const bf16x8*)&As[cur][aOff[m]];
#pragma unroll
        for (int f = 0; f < 4; ++f) {
            bf16x8 b = *(const bf16x8*)&Bs[cur][bOff[f]];
#pragma unroll
            for (int m = 0; m < 4; ++m)
                acc[m][f] = __builtin_amdgcn_mfma_f32_16x16x32_bf16(a[m], b, acc[m][f], 0, 0, 0);
        }
    }

#pragma unroll
    for (int m = 0; m < 4; ++m) {
        const int row0 = rowBlk + wm * 64 + m * 16 + lq * 4;
        if constexpr (MODE == 0) {
#pragma unroll
            for (int ob = 0; ob < 2; ++ob) {
                const int col = o0 + ob * 32 + wn * 16 + lr;
                const float bc = bp[col], bo = bp[256 + col];
#pragma unroll
                for (int j = 0; j < 4; ++j) {
                    int row = row0 + j;
                    if (row < M) {
                        float cv = acc[m][ob][j] + bc;
                        float ov = acc[m][2 + ob][j] + bo;
                        c_out[(size_t)row * 256 + col] = __float2half(cv);
                        h_out[(size_t)row * 256 + col] = f2bf(fsig(ov) * ftanh(cv));
                    }
                }
            }
        } else {
            const int col = o0 + wn * 16 + lr;
            const float bi  = bp[col],       blf = bp[256 + col];
            const float brf = bp[512 + col], bu  = bp[768 + col];
#pragma unroll
            for (int j = 0; j < 4; ++j) {
                int row = row0 + j;
                if (row < M) {
                    float gi = fsig(acc[m][0][j] + bi);
                    float lf = fsig(acc[m][1][j] + blf);
                    float rf = fsig(acc[m][2][j] + brf);
                    float gu = ftanh(acc[m][3][j] + bu);
                    float lc = __half2float(Cprev[(size_t)row * 512 + col]);
                    float rc = __half2float(Cprev[(size_t)row * 512 + 256 + col]);
                    float cv = gi * gu + lf * lc + rf * rc;
                    c_out[(size_t)row * 256 + col] = __float2half(cv);
                    h_out[(size_t)row * 256 + col] = f2bf(ftanh(cv));
                }
            }
        }
    }
}

// ---------------- tail: out-np 32..1, one block per batch, ks-rotated ----------------
// rot = blockIdx>>3: the 8 blocks sharing an XCD (b%8 round-robin) walk the
// weight stream at 8 distinct K-offsets -> no same-line L2 slice lockstep.

__global__ __launch_bounds__(512, 1)
void tail_lstm(const ushort* __restrict__ hin,   // (4096,256) bf16: 64 x 64 nodes
               const __half* __restrict__ cin,   // (4096,256) fp16
               const ushort* __restrict__ Wb,    // packed level weights
               const float* __restrict__ bp,     // (1024)
               float* __restrict__ dout)
{
    __shared__ __align__(16) ushort HA[32 * 256];
    __shared__ __align__(16) float  CA[32 * 256];
    __shared__ __align__(16) ushort HB[16 * 256];
    __shared__ __align__(16) float  CB[16 * 256];

    const int b = blockIdx.x;
    const int tid = threadIdx.x;
    const int wid = tid >> 6, ln = tid & 63;
    const int lq = ln >> 4, lr = ln & 15;
    const int rot = (b >> 3) & 15;     // 0..7: distinct within each XCD cohort

    int o_[2], sl_[2];
    const ushort* bB[2];
#pragma unroll
    for (int of = 0; of < 2; ++of) {
        o_[of] = wid * 32 + of * 16 + lr;
        sl_[of] = lq ^ ((o_[of] >> 1) & 3);
        bB[of] = Wb + (size_t)(o_[of] * 4 + sl_[of]) * 8;
    }
    const float bi0  = bp[o_[0]],       blf0 = bp[256 + o_[0]];
    const float brf0 = bp[512 + o_[0]], bu0  = bp[768 + o_[0]];
    const float bi1  = bp[o_[1]],       blf1 = bp[256 + o_[1]];
    const float brf1 = bp[512 + o_[1]], bu1  = bp[768 + o_[1]];

    // ---- prologue level: np_out = 32 (MC = 2), input from global, ks-rotated
    {
        const ushort* hbase = hin + (size_t)b * 64 * 256;
        f32x4 acc[2][2][4];
#pragma unroll
        for (int m = 0; m < 2; ++m)
#pragma unroll
            for (int of = 0; of < 2; ++of)
#pragma unroll
                for (int g = 0; g < 4; ++g) acc[m][of][g] = f32x4{0.f, 0.f, 0.f, 0.f};

        bf16x8 b0[2][4], b1[2][4], a0[2], a1[2];
        {
            const int k0 = rot;
#pragma unroll
            for (int of = 0; of < 2; ++of)
#pragma unroll
                for (int g = 0; g < 4; ++g)
                    b0[of][g] = *(const bf16x8*)(bB[of] + (size_t)(k0 * 4 + g) * 8192);
#pragma unroll
            for (int m = 0; m < 2; ++m) {
                int pr = 32 * m + 2 * lr + (k0 >> 3);
                int pc = lq + (k0 & 7) * 4;
                a0[m] = *(const bf16x8*)(hbase + (size_t)pr * 256 + pc * 8);
            }
        }

#pragma unroll 1
        for (int kk = 0; kk < 16; kk += 2) {
            if (kk + 1 < 16) {
                const int k1 = (kk + 1 + rot) & 15;
#pragma unroll
                for (int of = 0; of < 2; ++of)
#pragma unroll
                    for (int g = 0; g < 4; ++g)
                        b1[of][g] = *(const bf16x8*)(bB[of] + (size_t)(k1 * 4 + g) * 8192);
#pragma unroll
                for (int m = 0; m < 2; ++m) {
                    int pr = 32 * m + 2 * lr + (k1 >> 3);
                    int pc = lq + (k1 & 7) * 4;
                    a1[m] = *(const bf16x8*)(hbase + (size_t)pr * 256 + pc * 8);
                }
            }
#pragma unroll
            for (int m = 0; m < 2; ++m)
#pragma unroll
                for (int of = 0; of < 2; ++of)
#pragma unroll
                    for (int g = 0; g < 4; ++g)
                        acc[m][of][g] = __builtin_amdgcn_mfma_f32_16x16x32_bf16(a0[m], b0[of][g], acc[m][of][g], 0, 0, 0);
            if (kk + 2 < 16) {
                const int k2 = (kk + 2 + rot) & 15;
#pragma unroll
                for (int of = 0; of < 2; ++of)
#pragma unroll
                    for (int g = 0; g < 4; ++g)
                        b0[of][g] = *(const bf16x8*)(bB[of] + (size_t)(k2 * 4 + g) * 8192);
#pragma unroll
                for (int m = 0; m < 2; ++m) {
                    int pr = 32 * m + 2 * lr + (k2 >> 3);
                    int pc = lq + (k2 & 7) * 4;
                    a0[m] = *(const bf16x8*)(hbase + (size_t)pr * 256 + pc * 8);
                }
            }
#pragma unroll
            for (int m = 0; m < 2; ++m)
#pragma unroll
                for (int of = 0; of < 2; ++of)
#pragma unroll
                    for (int g = 0; g < 4; ++g)
                        acc[m][of][g] = __builtin_amdgcn_mfma_f32_16x16x32_bf16(a1[m], b1[of][g], acc[m][of][g], 0, 0, 0);
        }

        const __half* cbase = cin + (size_t)b * 64 * 256;
#pragma unroll
        for (int m = 0; m < 2; ++m)
#pragma unroll
        for (int of = 0; of < 2; ++of) {
            const int col = o_[of];
            const float vbi  = of ? bi1 : bi0,   vblf = of ? blf1 : blf0;
            const float vbrf = of ? brf1 : brf0, vbu  = of ? bu1 : bu0;
#pragma unroll
            for (int j = 0; j < 4; ++j) {
                int row = m * 16 + lq * 4 + j;
                float gi = fsig(acc[m][of][0][j] + vbi);
                float lf = fsig(acc[m][of][1][j] + vblf);
                float rf = fsig(acc[m][of][2][j] + vbrf);
                float gu = ftanh(acc[m][of][3][j] + vbu);
                float lc = __half2float(cbase[(size_t)(2 * row) * 256 + col]);
                float rc = __half2float(cbase[(size_t)(2 * row + 1) * 256 + col]);
                float cv = gi * gu + lf * lc + rf * rc;
                float hv = ftanh(cv);
                CA[row * 256 + col] = cv;
                HA[row * 256 + (((col >> 3) ^ ((row >> 1) & 7)) * 8) + (col & 7)] = f2bf(hv);
            }
        }
        __syncthreads();
    }

    // ---- dynamic levels: np_out = 16..1, ks-rotated
#pragma unroll 1
    for (int lvl = 1; lvl < 6; ++lvl) {
        const int npo = 32 >> lvl;
        const ushort* Hin = (lvl & 1) ? HA : HB;
        ushort*       Hout = (lvl & 1) ? HB : HA;
        const float*  Cin = (lvl & 1) ? CA : CB;
        float*        Cout = (lvl & 1) ? CB : CA;

        f32x4 acc[2][4];
#pragma unroll
        for (int of = 0; of < 2; ++of)
#pragma unroll
            for (int g = 0; g < 4; ++g) acc[of][g] = f32x4{0.f, 0.f, 0.f, 0.f};

        bf16x8 b0[2][4], b1[2][4], a0, a1;
        {
            const int k0 = rot;
#pragma unroll
            for (int of = 0; of < 2; ++of)
#pragma unroll
                for (int g = 0; g < 4; ++g)
                    b0[of][g] = *(const bf16x8*)(bB[of] + (size_t)(k0 * 4 + g) * 8192);
            int pr = 2 * lr + (k0 >> 3), pc = lq + (k0 & 7) * 4;
            a0 = *(const bf16x8*)&Hin[pr * 256 + ((pc ^ ((pr >> 1) & 7)) * 8)];
        }

#pragma unroll 1
        for (int kk = 0; kk < 16; kk += 2) {
            if (kk + 1 < 16) {
                const int k1 = (kk + 1 + rot) & 15;
#pragma unroll
                for (int of = 0; of < 2; ++of)
#pragma unroll
                    for (int g = 0; g < 4; ++g)
                        b1[of][g] = *(const bf16x8*)(bB[of] + (size_t)(k1 * 4 + g) * 8192);
                int pr = 2 * lr + (k1 >> 3), pc = lq + (k1 & 7) * 4;
                a1 = *(const bf16x8*)&Hin[pr * 256 + ((pc ^ ((pr >> 1) & 7)) * 8)];
            }
#pragma unroll
            for (int of = 0; of < 2; ++of)
#pragma unroll
                for (int g = 0; g < 4; ++g)
                    acc[of][g] = __builtin_amdgcn_mfma_f32_16x16x32_bf16(a0, b0[of][g], acc[of][g], 0, 0, 0);
            if (kk + 2 < 16) {
                const int k2 = (kk + 2 + rot) & 15;
#pragma unroll
                for (int of = 0; of < 2; ++of)
#pragma unroll
                    for (int g = 0; g < 4; ++g)
                        b0[of][g] = *(const bf16x8*)(bB[of] + (size_t)(k2 * 4 + g) * 8192);
                int pr = 2 * lr + (k2 >> 3), pc = lq + (k2 & 7) * 4;
                a0 = *(const bf16x8*)&Hin[pr * 256 + ((pc ^ ((pr >> 1) & 7)) * 8)];
            }
#pragma unroll
            for (int of = 0; of < 2; ++of)
#pragma unroll
                for (int g = 0; g < 4; ++g)
                    acc[of][g] = __builtin_amdgcn_mfma_f32_16x16x32_bf16(a1, b1[of][g], acc[of][g], 0, 0, 0);
        }

#pragma unroll
        for (int of = 0; of < 2; ++of) {
            const int col = o_[of];
            const float vbi  = of ? bi1 : bi0,   vblf = of ? blf1 : blf0;
            const float vbrf = of ? brf1 : brf0, vbu  = of ? bu1 : bu0;
#pragma unroll
            for (int j = 0; j < 4; ++j) {
                int row = lq * 4 + j;
                if (row < npo) {
                    float gi = fsig(acc[of][0][j] + vbi);
                    float lf = fsig(acc[of][1][j] + vblf);
                    float rf = fsig(acc[of][2][j] + vbrf);
                    float gu = ftanh(acc[of][3][j] + vbu);
                    float lc = Cin[(2 * row) * 256 + col];
                    float rc = Cin[(2 * row + 1) * 256 + col];
                    float cv = gi * gu + lf * lc + rf * rc;
                    float hv = ftanh(cv);
                    if (lvl == 5) {
                        dout[b * 256 + col] = cv;
                        dout[16384 + b * 256 + col] = hv;
                    } else {
                        Cout[row * 256 + col] = cv;
                        Hout[row * 256 + (((col >> 3) ^ ((row >> 1) & 7)) * 8) + (col & 7)] = f2bf(hv);
                    }
                }
            }
        }
        __syncthreads();
    }
}

// ---------------- host ----------------

extern "C" void kernel_launch(void* const* d_in, const int* in_sizes, int n_in,
                              void* d_out, int out_size, void* d_ws, size_t ws_size,
                              hipStream_t stream)
{
    const float* embs = (const float*)d_in[0];
    const float* Wcx  = (const float*)d_in[1];
    const float* bcx  = (const float*)d_in[2];
    const float* Wox  = (const float*)d_in[3];
    const float* box  = (const float*)d_in[4];
    const float* Wl   = (const float*)d_in[5];
    const float* bl   = (const float*)d_in[6];
    const float* Wr   = (const float*)d_in[7];
    const float* br   = (const float*)d_in[8];

    char* p = (char*)d_ws;
    ushort* Wb2 = (ushort*)p;  p += (size_t)524288 * 2;
    ushort* WbL = (ushort*)p;  p += (size_t)163840 * 2;
    float*  bp2 = (float*)p;   p += 1024 * 4;
    float*  bpL = (float*)p;   p += 512 * 4;
    __half* c0  = (__half*)p;  p += (size_t)65536 * 256 * 2;   // 32 MB
    ushort* h0  = (ushort*)p;  p += (size_t)65536 * 256 * 2;   // 32 MB
    char* X = p;
    ushort* embsB = (ushort*)X;                                 // 40 MB (dead after leaf)
    __half* cA = (__half*)X;                                    // 16 MB (32768,256)
    ushort* hA = (ushort*)(X + (size_t)16 * 1024 * 1024);       // 16 MB
    __half* cB = (__half*)(X + (size_t)32 * 1024 * 1024);       //  8 MB (16384,256)
    ushort* hB = (ushort*)(X + (size_t)40 * 1024 * 1024);       //  8 MB

    prep<<<1024, 256, 0, stream>>>(Wl, Wr, bl, br, Wcx, Wox, bcx, box, embs,
                                   Wb2, WbL, bp2, bpL, embsB);

    // leaf: (65536,320) @ (320, 2*256) -> c0 fp16, h0 bf16
    mfma_gemm<2, 10, 0><<<dim3(512, 4), 256, 0, stream>>>(
        embsB, WbL, bpL, nullptr, c0, h0, 65536);

    // np=512: h0 (32768,512), c0 -> cA,hA
    mfma_gemm<4, 16, 1><<<dim3(256, 8), 256, 0, stream>>>(
        h0, Wb2, bp2, c0, cA, hA, 32768);
    // np=256: hA, cA -> cB,hB
    mfma_gemm<4, 16, 1><<<dim3(128, 8), 256, 0, stream>>>(
        hA, Wb2, bp2, cA, cB, hB, 16384);
    // np=128: hB, cB -> cA,hA
    mfma_gemm<4, 16, 1><<<dim3(64, 8), 256, 0, stream>>>(
        hB, Wb2, bp2, cB, cA, hA, 8192);
    // np=64: hA, cA -> cB,hB
    mfma_gemm<4, 16, 1><<<dim3(32, 8), 256, 0, stream>>>(
        hA, Wb2, bp2, cA, cB, hB, 4096);

    // tail: np 32..1 (input hB (4096,256) bf16, cB fp16) -> d_out
    tail_lstm<<<64, 512, 0, stream>>>(
        hB, cB, Wb2, bp2, (float*)d_out);
}